// Round 5
// baseline (165.145 us; speedup 1.0000x reference)
//
#include <hip/hip_runtime.h>
#include <hip/hip_bf16.h>

#define IN_F 4096
#define LOCAL_F 128
#define KSZ 64
#define STRIDE_ 32
#define FOLDS 127
#define BATCH_ 4096
#define OUT_F (FOLDS * LOCAL_F)    // 16256
#define WN (FOLDS * LOCAL_F * KSZ) // 1040384

typedef __attribute__((ext_vector_type(8))) short bf16x8;
typedef __attribute__((ext_vector_type(8))) unsigned short u16x8;
typedef __attribute__((ext_vector_type(4))) float f32x4;

__device__ __forceinline__ unsigned short f2bf(float f) {
    unsigned u = __builtin_bit_cast(unsigned, f);
    u += 0x7fffu + ((u >> 16) & 1u);   // round-to-nearest-even
    return (unsigned short)(u >> 16);
}

// ---- prep: W fp32 -> bf16 (4 MB read / 2 MB write, ~1 us) ----
__global__ __launch_bounds__(256)
void wprep_kernel(const float* __restrict__ W, unsigned short* __restrict__ Wbf) {
    int i = (blockIdx.x * 256 + threadIdx.x) * 8;
    if (i >= WN) return;
    float4 a = *reinterpret_cast<const float4*>(W + i);
    float4 c = *reinterpret_cast<const float4*>(W + i + 4);
    u16x8 s;
    s[0] = f2bf(a.x); s[1] = f2bf(a.y); s[2] = f2bf(a.z); s[3] = f2bf(a.w);
    s[4] = f2bf(c.x); s[5] = f2bf(c.y); s[6] = f2bf(c.z); s[7] = f2bf(c.w);
    *reinterpret_cast<u16x8*>(Wbf + i) = s;
}

// ---- main: block = 16 batch rows x 32 folds; wave w -> folds fq*32 + w + 4j ----
// No LDS, no barriers. Each block's output footprint: 16 rows x 16 KB CONTIGUOUS.
__global__ __launch_bounds__(256, 4)
void ll_main(const float* __restrict__ x,
             const unsigned short* __restrict__ Wbf,
             const float* __restrict__ b,
             float* __restrict__ out) {
    const int rg = blockIdx.x;            // 0..255: 16-row batch group
    const int fq = blockIdx.y;            // 0..3:  32-fold quarter
    const int row0 = rg * 16;

    const int wave = threadIdx.x >> 6;
    const int lane = threadIdx.x & 63;
    const int l16 = lane & 15;
    const int g   = lane >> 4;

    const float* xrow = x + (size_t)(row0 + l16) * IN_F;   // lane's batch row (reads)
    float*       orow = out + (size_t)(row0 + l16) * OUT_F; // lane's batch row (writes)

    #pragma unroll
    for (int j = 0; j < 8; ++j) {
        const int f = fq * 32 + wave + 4 * j;
        if (f >= FOLDS) break;            // only fq=3, wave=3, j=7

        // ---- x fragments: lane holds x[row0+l16][f*32 + ks*32 + g*8 + 0..7] ----
        bf16x8 af[2];
        #pragma unroll
        for (int ks = 0; ks < 2; ++ks) {
            const float* p = xrow + f * STRIDE_ + ks * 32 + g * 8;
            float4 a = *reinterpret_cast<const float4*>(p);
            float4 c = *reinterpret_cast<const float4*>(p + 4);
            bf16x8 t;
            t[0] = (short)f2bf(a.x); t[1] = (short)f2bf(a.y);
            t[2] = (short)f2bf(a.z); t[3] = (short)f2bf(a.w);
            t[4] = (short)f2bf(c.x); t[5] = (short)f2bf(c.y);
            t[6] = (short)f2bf(c.z); t[7] = (short)f2bf(c.w);
            af[ks] = t;
        }

        f32x4 acc[8];
        #pragma unroll
        for (int nt = 0; nt < 8; ++nt) acc[nt] = (f32x4){0.f, 0.f, 0.f, 0.f};

        const unsigned short* Wf = Wbf + (size_t)f * (LOCAL_F * KSZ);
        #pragma unroll
        for (int ks = 0; ks < 2; ++ks) {
            // W fragment: lane holds W[f][nt*16 + l16][ks*32 + g*8 + 0..7] (L2-resident)
            bf16x8 wf[8];
            #pragma unroll
            for (int nt = 0; nt < 8; ++nt)
                wf[nt] = *reinterpret_cast<const bf16x8*>(Wf + (nt * 16 + l16) * KSZ + ks * 32 + g * 8);
            // D = W x X^T : lane holds D[feat = nt*16 + 4g + i][batch = l16]
            #pragma unroll
            for (int nt = 0; nt < 8; ++nt)
                acc[nt] = __builtin_amdgcn_mfma_f32_16x16x32_bf16(wf[nt], af[ks], acc[nt], 0, 0, 0);
        }

        // ---- bias + stores: lane writes 4 consecutive floats in its own row ----
        #pragma unroll
        for (int nt = 0; nt < 8; ++nt) {
            f32x4 bv = *reinterpret_cast<const f32x4*>(b + (size_t)f * LOCAL_F + nt * 16 + 4 * g);
            f32x4 v = acc[nt] + bv;
            *reinterpret_cast<f32x4*>(orow + (size_t)f * LOCAL_F + nt * 16 + 4 * g) = v;
        }
    }
}

extern "C" void kernel_launch(void* const* d_in, const int* in_sizes, int n_in,
                              void* d_out, int out_size, void* d_ws, size_t ws_size,
                              hipStream_t stream) {
    const float* x = (const float*)d_in[0];
    const float* W = (const float*)d_in[1];
    const float* b = (const float*)d_in[2];
    float* out = (float*)d_out;
    unsigned short* Wbf = (unsigned short*)d_ws;

    wprep_kernel<<<(WN / 8 + 255) / 256, 256, 0, stream>>>(W, Wbf);
    dim3 grid(BATCH_ / 16, 4);
    ll_main<<<grid, 256, 0, stream>>>(x, Wbf, b, out);
}

// Round 6
// 164.568 us; speedup vs baseline: 1.0035x; 1.0035x over previous
//
#include <hip/hip_runtime.h>
#include <hip/hip_bf16.h>

#define IN_F 4096
#define LOCAL_F 128
#define KSZ 64
#define STRIDE_ 32
#define FOLDS 127
#define BATCH_ 4096
#define OUT_F (FOLDS * LOCAL_F)    // 16256
#define WN (FOLDS * LOCAL_F * KSZ) // 1040384

typedef __attribute__((ext_vector_type(8))) short bf16x8;
typedef __attribute__((ext_vector_type(8))) unsigned short u16x8;
typedef __attribute__((ext_vector_type(4))) float f32x4;

__device__ __forceinline__ unsigned short f2bf(float f) {
    unsigned u = __builtin_bit_cast(unsigned, f);
    u += 0x7fffu + ((u >> 16) & 1u);   // round-to-nearest-even
    return (unsigned short)(u >> 16);
}

// ---- prep: W fp32 -> bf16 (4 MB read / 2 MB write) ----
__global__ __launch_bounds__(256)
void wprep_kernel(const float* __restrict__ W, unsigned short* __restrict__ Wbf) {
    int i = (blockIdx.x * 256 + threadIdx.x) * 8;
    if (i >= WN) return;
    float4 a = *reinterpret_cast<const float4*>(W + i);
    float4 c = *reinterpret_cast<const float4*>(W + i + 4);
    u16x8 s;
    s[0] = f2bf(a.x); s[1] = f2bf(a.y); s[2] = f2bf(a.z); s[3] = f2bf(a.w);
    s[4] = f2bf(c.x); s[5] = f2bf(c.y); s[6] = f2bf(c.z); s[7] = f2bf(c.w);
    *reinterpret_cast<u16x8*>(Wbf + i) = s;
}

// ---- main: wave = ONE fold x 16 batch rows, straight-line, all loads up-front ----
// grid (256 row-groups, 32 fold-quarters), block = 4 waves = folds fq*4 + wave.
// No LDS, no barriers, no loops over memory -> ~20 VMEM in flight per wave.
__global__ __launch_bounds__(256, 3)
void ll_main(const float* __restrict__ x,
             const unsigned short* __restrict__ Wbf,
             const float* __restrict__ b,
             float* __restrict__ out) {
    const int rg = blockIdx.x;            // 0..255
    const int fq = blockIdx.y;            // 0..31
    const int row0 = rg * 16;

    const int wave = threadIdx.x >> 6;
    const int lane = threadIdx.x & 63;
    const int f = fq * 4 + wave;
    if (f >= FOLDS) return;               // only fq=31, wave=3; no barriers -> safe

    const int l16 = lane & 15;
    const int g   = lane >> 4;

    // ---- issue ALL loads up-front ----
    // x: lane holds x[row0+l16][f*32 + ks*32 + g*8 + 0..7]  (fp32, 4 float4 loads)
    const float* xp = x + (size_t)(row0 + l16) * IN_F + f * STRIDE_ + g * 8;
    float4 xa0 = *reinterpret_cast<const float4*>(xp);
    float4 xa1 = *reinterpret_cast<const float4*>(xp + 4);
    float4 xb0 = *reinterpret_cast<const float4*>(xp + 32);
    float4 xb1 = *reinterpret_cast<const float4*>(xp + 36);

    // W: lane holds W[f][nt*16 + l16][ks*32 + g*8 + 0..7]  (16 x 16B loads, L2)
    const unsigned short* Wf = Wbf + (size_t)f * (LOCAL_F * KSZ) + l16 * KSZ + g * 8;
    bf16x8 wf[2][8];
    #pragma unroll
    for (int nt = 0; nt < 8; ++nt) {
        wf[0][nt] = *reinterpret_cast<const bf16x8*>(Wf + nt * 16 * KSZ);
        wf[1][nt] = *reinterpret_cast<const bf16x8*>(Wf + nt * 16 * KSZ + 32);
    }

    // bias: lane needs b[f*128 + nt*16 + 4g + 0..3]
    f32x4 bv[8];
    #pragma unroll
    for (int nt = 0; nt < 8; ++nt)
        bv[nt] = *reinterpret_cast<const f32x4*>(b + (size_t)f * LOCAL_F + nt * 16 + 4 * g);

    // ---- convert x to bf16 fragments ----
    bf16x8 af[2];
    {
        bf16x8 t;
        t[0] = (short)f2bf(xa0.x); t[1] = (short)f2bf(xa0.y);
        t[2] = (short)f2bf(xa0.z); t[3] = (short)f2bf(xa0.w);
        t[4] = (short)f2bf(xa1.x); t[5] = (short)f2bf(xa1.y);
        t[6] = (short)f2bf(xa1.z); t[7] = (short)f2bf(xa1.w);
        af[0] = t;
        t[0] = (short)f2bf(xb0.x); t[1] = (short)f2bf(xb0.y);
        t[2] = (short)f2bf(xb0.z); t[3] = (short)f2bf(xb0.w);
        t[4] = (short)f2bf(xb1.x); t[5] = (short)f2bf(xb1.y);
        t[6] = (short)f2bf(xb1.z); t[7] = (short)f2bf(xb1.w);
        af[1] = t;
    }

    // ---- MFMA: D = W x X^T ; lane holds D[feat = nt*16 + 4g + i][batch = l16] ----
    f32x4 acc[8];
    #pragma unroll
    for (int nt = 0; nt < 8; ++nt) acc[nt] = (f32x4){0.f, 0.f, 0.f, 0.f};
    #pragma unroll
    for (int nt = 0; nt < 8; ++nt)
        acc[nt] = __builtin_amdgcn_mfma_f32_16x16x32_bf16(wf[0][nt], af[0], acc[nt], 0, 0, 0);
    #pragma unroll
    for (int nt = 0; nt < 8; ++nt)
        acc[nt] = __builtin_amdgcn_mfma_f32_16x16x32_bf16(wf[1][nt], af[1], acc[nt], 0, 0, 0);

    // ---- bias + stores: lane writes 4 consecutive floats in its own batch row ----
    float* orow = out + (size_t)(row0 + l16) * OUT_F + f * LOCAL_F + 4 * g;
    #pragma unroll
    for (int nt = 0; nt < 8; ++nt) {
        f32x4 v = acc[nt] + bv[nt];
        *reinterpret_cast<f32x4*>(orow + nt * 16) = v;
    }
}

extern "C" void kernel_launch(void* const* d_in, const int* in_sizes, int n_in,
                              void* d_out, int out_size, void* d_ws, size_t ws_size,
                              hipStream_t stream) {
    const float* x = (const float*)d_in[0];
    const float* W = (const float*)d_in[1];
    const float* b = (const float*)d_in[2];
    float* out = (float*)d_out;
    unsigned short* Wbf = (unsigned short*)d_ws;

    wprep_kernel<<<(WN / 8 + 255) / 256, 256, 0, stream>>>(W, Wbf);
    dim3 grid(BATCH_ / 16, 32);
    ll_main<<<grid, 256, 0, stream>>>(x, Wbf, b, out);
}

// Round 7
// 127.179 us; speedup vs baseline: 1.2985x; 1.2940x over previous
//
#include <hip/hip_runtime.h>
#include <hip/hip_bf16.h>

#define IN_F 4096
#define LOCAL_F 128
#define KSZ 64
#define STRIDE_ 32
#define FOLDS 127
#define BATCH_ 4096
#define OUT_F (FOLDS * LOCAL_F)    // 16256
#define WN (FOLDS * LOCAL_F * KSZ) // 1040384

#define ROWS 16
#define FPB 8                       // folds per block
#define LDSW (FPB * LOCAL_F + 4)    // 1028 floats: +4 pad -> conflict-free phased b128

typedef __attribute__((ext_vector_type(8))) short bf16x8;
typedef __attribute__((ext_vector_type(8))) unsigned short u16x8;
typedef __attribute__((ext_vector_type(4))) float f32x4;

__device__ __forceinline__ unsigned short f2bf(float f) {
    unsigned u = __builtin_bit_cast(unsigned, f);
    u += 0x7fffu + ((u >> 16) & 1u);   // round-to-nearest-even
    return (unsigned short)(u >> 16);
}

// ---- prep: W fp32 -> bf16 (4 MB read / 2 MB write) ----
__global__ __launch_bounds__(256)
void wprep_kernel(const float* __restrict__ W, unsigned short* __restrict__ Wbf) {
    int i = (blockIdx.x * 256 + threadIdx.x) * 8;
    if (i >= WN) return;
    float4 a = *reinterpret_cast<const float4*>(W + i);
    float4 c = *reinterpret_cast<const float4*>(W + i + 4);
    u16x8 s;
    s[0] = f2bf(a.x); s[1] = f2bf(a.y); s[2] = f2bf(a.z); s[3] = f2bf(a.w);
    s[4] = f2bf(c.x); s[5] = f2bf(c.y); s[6] = f2bf(c.z); s[7] = f2bf(c.w);
    *reinterpret_cast<u16x8*>(Wbf + i) = s;
}

// ---- main: block = 16 rows x 8 folds; MFMA compute -> LDS tile -> DENSE row bursts ----
// Epilogue writes 4 KB fully contiguous per row per block (fill-kernel-like pattern).
__global__ __launch_bounds__(256, 2)
void ll_main(const float* __restrict__ x,
             const unsigned short* __restrict__ Wbf,
             const float* __restrict__ b,
             float* __restrict__ out) {
    __shared__ float os[ROWS][LDSW];

    const int fqb = blockIdx.x;           // 0..15  (fold group: folds fqb*8 .. fqb*8+7)
    const int rg  = blockIdx.y;           // 0..255 (16-row batch band)
    const int row0 = rg * ROWS;

    const int wave = threadIdx.x >> 6;
    const int lane = threadIdx.x & 63;
    const int l16 = lane & 15;
    const int g   = lane >> 4;

    #pragma unroll
    for (int p = 0; p < 2; ++p) {
        const int fl = wave * 2 + p;      // fold-local 0..7
        const int f  = fqb * FPB + fl;
        if (f < FOLDS) {
            // ---- x fragments: lane holds x[row0+l16][f*32 + ks*32 + g*8 + 0..7] ----
            const float* xp = x + (size_t)(row0 + l16) * IN_F + f * STRIDE_ + g * 8;
            float4 xa0 = *reinterpret_cast<const float4*>(xp);
            float4 xa1 = *reinterpret_cast<const float4*>(xp + 4);
            float4 xb0 = *reinterpret_cast<const float4*>(xp + 32);
            float4 xb1 = *reinterpret_cast<const float4*>(xp + 36);

            // ---- W fragments: lane holds W[f][nt*16 + l16][ks*32 + g*8 + 0..7] ----
            const unsigned short* Wf = Wbf + (size_t)f * (LOCAL_F * KSZ) + l16 * KSZ + g * 8;
            bf16x8 wf[2][8];
            #pragma unroll
            for (int nt = 0; nt < 8; ++nt) {
                wf[0][nt] = *reinterpret_cast<const bf16x8*>(Wf + nt * 16 * KSZ);
                wf[1][nt] = *reinterpret_cast<const bf16x8*>(Wf + nt * 16 * KSZ + 32);
            }

            bf16x8 af0, af1;
            af0[0] = (short)f2bf(xa0.x); af0[1] = (short)f2bf(xa0.y);
            af0[2] = (short)f2bf(xa0.z); af0[3] = (short)f2bf(xa0.w);
            af0[4] = (short)f2bf(xa1.x); af0[5] = (short)f2bf(xa1.y);
            af0[6] = (short)f2bf(xa1.z); af0[7] = (short)f2bf(xa1.w);
            af1[0] = (short)f2bf(xb0.x); af1[1] = (short)f2bf(xb0.y);
            af1[2] = (short)f2bf(xb0.z); af1[3] = (short)f2bf(xb0.w);
            af1[4] = (short)f2bf(xb1.x); af1[5] = (short)f2bf(xb1.y);
            af1[6] = (short)f2bf(xb1.z); af1[7] = (short)f2bf(xb1.w);

            // ---- MFMA: D = W x X^T ; lane holds D[feat = nt*16 + 4g + i][batch = l16]
            f32x4 acc[8];
            #pragma unroll
            for (int nt = 0; nt < 8; ++nt) acc[nt] = (f32x4){0.f, 0.f, 0.f, 0.f};
            #pragma unroll
            for (int nt = 0; nt < 8; ++nt)
                acc[nt] = __builtin_amdgcn_mfma_f32_16x16x32_bf16(wf[0][nt], af0, acc[nt], 0, 0, 0);
            #pragma unroll
            for (int nt = 0; nt < 8; ++nt)
                acc[nt] = __builtin_amdgcn_mfma_f32_16x16x32_bf16(wf[1][nt], af1, acc[nt], 0, 0, 0);

            // ---- bias + stage to LDS: os[row=l16][fl*128 + nt*16 + 4g + 0..3] ----
            #pragma unroll
            for (int nt = 0; nt < 8; ++nt) {
                f32x4 bv = *reinterpret_cast<const f32x4*>(b + (size_t)f * LOCAL_F + nt * 16 + 4 * g);
                f32x4 v = acc[nt] + bv;
                *reinterpret_cast<f32x4*>(&os[l16][fl * LOCAL_F + nt * 16 + 4 * g]) = v;
            }
        }
    }
    __syncthreads();

    // ---- dense epilogue: per row, 256 threads write one 4-KB contiguous burst ----
    const int t = threadIdx.x;
    const int colbase = fqb * (FPB * LOCAL_F);   // fqb*1024
    const int col = colbase + 4 * t;
    #pragma unroll
    for (int r = 0; r < ROWS; ++r) {
        if (col < OUT_F) {
            f32x4 v = *reinterpret_cast<const f32x4*>(&os[r][4 * t]);
            *reinterpret_cast<f32x4*>(out + (size_t)(row0 + r) * OUT_F + col) = v;
        }
    }
}

extern "C" void kernel_launch(void* const* d_in, const int* in_sizes, int n_in,
                              void* d_out, int out_size, void* d_ws, size_t ws_size,
                              hipStream_t stream) {
    const float* x = (const float*)d_in[0];
    const float* W = (const float*)d_in[1];
    const float* b = (const float*)d_in[2];
    float* out = (float*)d_out;
    unsigned short* Wbf = (unsigned short*)d_ws;

    wprep_kernel<<<(WN / 8 + 255) / 256, 256, 0, stream>>>(W, Wbf);
    dim3 grid(16, BATCH_ / ROWS);   // fq fastest -> dense global write front
    ll_main<<<grid, 256, 0, stream>>>(x, Wbf, b, out);
}

// Round 8
// 102.419 us; speedup vs baseline: 1.6124x; 1.2417x over previous
//
#include <hip/hip_runtime.h>
#include <hip/hip_bf16.h>

#define IN_F 4096
#define LOCAL_F 128
#define KSZ 64
#define STRIDE_ 32
#define FOLDS 127
#define BATCH_ 4096
#define OUT_F (FOLDS * LOCAL_F)    // 16256
#define WN (FOLDS * LOCAL_F * KSZ) // 1040384

#define ROWS 16
#define FPB 8                       // folds per block
#define LDSW (FPB * LOCAL_F + 4)    // 1028 floats: +4 pad -> conflict-free b128

typedef __attribute__((ext_vector_type(8))) short bf16x8;
typedef __attribute__((ext_vector_type(8))) unsigned short u16x8;
typedef __attribute__((ext_vector_type(4))) float f32x4;

__device__ __forceinline__ unsigned short f2bf(float f) {
    unsigned u = __builtin_bit_cast(unsigned, f);
    u += 0x7fffu + ((u >> 16) & 1u);   // round-to-nearest-even
    return (unsigned short)(u >> 16);
}

// ---- prep: W fp32 -> bf16 (4 MB read / 2 MB write) ----
__global__ __launch_bounds__(256)
void wprep_kernel(const float* __restrict__ W, unsigned short* __restrict__ Wbf) {
    int i = (blockIdx.x * 256 + threadIdx.x) * 8;
    if (i >= WN) return;
    float4 a = *reinterpret_cast<const float4*>(W + i);
    float4 c = *reinterpret_cast<const float4*>(W + i + 4);
    u16x8 s;
    s[0] = f2bf(a.x); s[1] = f2bf(a.y); s[2] = f2bf(a.z); s[3] = f2bf(a.w);
    s[4] = f2bf(c.x); s[5] = f2bf(c.y); s[6] = f2bf(c.z); s[7] = f2bf(c.w);
    *reinterpret_cast<u16x8*>(Wbf + i) = s;
}

// ---- main: block = 16 rows x 8 folds; MFMA -> LDS transpose -> DENSE NONTEMPORAL bursts ----
__global__ __launch_bounds__(256, 2)
void ll_main(const float* __restrict__ x,
             const unsigned short* __restrict__ Wbf,
             const float* __restrict__ b,
             float* __restrict__ out) {
    __shared__ float os[ROWS][LDSW];

    const int fqb = blockIdx.x;           // 0..15  (folds fqb*8 .. fqb*8+7)
    const int rg  = blockIdx.y;           // 0..255 (16-row batch band)
    const int row0 = rg * ROWS;

    const int wave = threadIdx.x >> 6;
    const int lane = threadIdx.x & 63;
    const int l16 = lane & 15;
    const int g   = lane >> 4;

    #pragma unroll
    for (int p = 0; p < 2; ++p) {
        const int fl = wave * 2 + p;      // fold-local 0..7
        const int f  = fqb * FPB + fl;
        if (f < FOLDS) {
            // ---- x fragments: lane holds x[row0+l16][f*32 + ks*32 + g*8 + 0..7] ----
            const float* xp = x + (size_t)(row0 + l16) * IN_F + f * STRIDE_ + g * 8;
            float4 xa0 = *reinterpret_cast<const float4*>(xp);
            float4 xa1 = *reinterpret_cast<const float4*>(xp + 4);
            float4 xb0 = *reinterpret_cast<const float4*>(xp + 32);
            float4 xb1 = *reinterpret_cast<const float4*>(xp + 36);

            // ---- W fragments: lane holds W[f][nt*16 + l16][ks*32 + g*8 + 0..7] ----
            const unsigned short* Wf = Wbf + (size_t)f * (LOCAL_F * KSZ) + l16 * KSZ + g * 8;
            bf16x8 wf[2][8];
            #pragma unroll
            for (int nt = 0; nt < 8; ++nt) {
                wf[0][nt] = *reinterpret_cast<const bf16x8*>(Wf + nt * 16 * KSZ);
                wf[1][nt] = *reinterpret_cast<const bf16x8*>(Wf + nt * 16 * KSZ + 32);
            }

            bf16x8 af0, af1;
            af0[0] = (short)f2bf(xa0.x); af0[1] = (short)f2bf(xa0.y);
            af0[2] = (short)f2bf(xa0.z); af0[3] = (short)f2bf(xa0.w);
            af0[4] = (short)f2bf(xa1.x); af0[5] = (short)f2bf(xa1.y);
            af0[6] = (short)f2bf(xa1.z); af0[7] = (short)f2bf(xa1.w);
            af1[0] = (short)f2bf(xb0.x); af1[1] = (short)f2bf(xb0.y);
            af1[2] = (short)f2bf(xb0.z); af1[3] = (short)f2bf(xb0.w);
            af1[4] = (short)f2bf(xb1.x); af1[5] = (short)f2bf(xb1.y);
            af1[6] = (short)f2bf(xb1.z); af1[7] = (short)f2bf(xb1.w);

            // ---- MFMA: D = W x X^T ; lane holds D[feat = nt*16 + 4g + i][batch = l16]
            f32x4 acc[8];
            #pragma unroll
            for (int nt = 0; nt < 8; ++nt) acc[nt] = (f32x4){0.f, 0.f, 0.f, 0.f};
            #pragma unroll
            for (int nt = 0; nt < 8; ++nt)
                acc[nt] = __builtin_amdgcn_mfma_f32_16x16x32_bf16(wf[0][nt], af0, acc[nt], 0, 0, 0);
            #pragma unroll
            for (int nt = 0; nt < 8; ++nt)
                acc[nt] = __builtin_amdgcn_mfma_f32_16x16x32_bf16(wf[1][nt], af1, acc[nt], 0, 0, 0);

            // ---- bias + stage to LDS: os[row=l16][fl*128 + nt*16 + 4g + 0..3] ----
            #pragma unroll
            for (int nt = 0; nt < 8; ++nt) {
                f32x4 bv = *reinterpret_cast<const f32x4*>(b + (size_t)f * LOCAL_F + nt * 16 + 4 * g);
                f32x4 v = acc[nt] + bv;
                *reinterpret_cast<f32x4*>(&os[l16][fl * LOCAL_F + nt * 16 + 4 * g]) = v;
            }
        }
    }
    __syncthreads();

    // ---- dense epilogue: per row, 256 threads write one 4-KB contiguous NT burst ----
    const int t = threadIdx.x;
    const int colbase = fqb * (FPB * LOCAL_F);   // fqb*1024
    const int col = colbase + 4 * t;
    #pragma unroll
    for (int r = 0; r < ROWS; ++r) {
        if (col < OUT_F) {
            f32x4 v = *reinterpret_cast<const f32x4*>(&os[r][4 * t]);
            __builtin_nontemporal_store(v,
                reinterpret_cast<f32x4*>(out + (size_t)(row0 + r) * OUT_F + col));
        }
    }
}

extern "C" void kernel_launch(void* const* d_in, const int* in_sizes, int n_in,
                              void* d_out, int out_size, void* d_ws, size_t ws_size,
                              hipStream_t stream) {
    const float* x = (const float*)d_in[0];
    const float* W = (const float*)d_in[1];
    const float* b = (const float*)d_in[2];
    float* out = (float*)d_out;
    unsigned short* Wbf = (unsigned short*)d_ws;

    wprep_kernel<<<(WN / 8 + 255) / 256, 256, 0, stream>>>(W, Wbf);
    dim3 grid(16, BATCH_ / ROWS);   // fqb fastest -> dense global write front
    ll_main<<<grid, 256, 0, stream>>>(x, Wbf, b, out);
}